// Round 6
// baseline (235.008 us; speedup 1.0000x reference)
//
#include <hip/hip_runtime.h>
#include <stdint.h>

// SAGEConv (mean aggr, no bias): out = segment_mean(x[src], dst) @ W_l + x @ W_r
// Pipeline (memset + 2 kernels):
//   memset : cursorB[1024*8] + degG[N] = 0 (433 KB)
//   k_prep : block-role split:
//              [0,EB)    : partition edges into padded dst-buckets (dst>>7)
//                          via DIRECT global-atomic slot claim (padded 32B
//                          cursors -> L2-slice parallel) + degG atomics.
//                          No LDS, no scan, no barriers.
//              [EB,EB+8) : Wl/Wr transpose -> bf16
//              [EB+8,..) : x -> bf16 (overlaps partition)
//   k_fused: per bucket (128 nodes): stream packed edges, LDS fixed-point
//            accumulation via PAIRED ds_add_u64 (fp32 LDS atomicAdd is a
//            CAS-loop disaster on gfx950; u64 int add is native)
//            -> mean -> bf16 -> MFMA GEMM: out = mean@Wl + x@Wr
//
// Magic-number fixed-point: bits(fmaf(xf, 2^19, 1.5*2^23)) = 0x4B400000 +
// round_ne(xf*2^19). lo half of u64: masked 23 bits (per-addend bias 2^22);
// hi half keeps 0x4B400000, wraps mod 2^32 (exact; removed as deg*const at
// epilogue). lo-half sum <= deg*2^23 < 2^32 for deg < 512 (Poisson(12) here,
// max ~45). Quantization 2^-19 ~ 2e-6 << 0.03 tol; integer adds commute ->
// bit-stable under nondeterministic slot order.
//
// Geometry: NPB=128 -> accI[128][66] = 33.8 KB LDS; 512 thr (8 waves) ->
// 4 blocks/CU = 32 waves/CU. Pairs packed u32 = src | (dl<<24).

#define FDIM 64
#define NPB 128      // nodes per bucket (bucket = dst>>7)
#define ACCW 66      // padded int row stride (even: u64-aligned rows)
#define NBKTP 1024   // cursor slots (782 used), stride 8 ints (32 B pad)
#define CAP 2048     // per-bucket edge capacity (avg 1535, sd ~39 -> +13 sigma)
#define CAPSH 11
#define FPS 524288.0f        // 2^19
#define FPINV (1.0f / 524288.0f)
#define MAGICF 12582912.0f   // 1.5 * 2^23
#define LOB 0x00400000u      // per-addend lo bias 2^22
#define HIB 0x4B400000u      // per-addend hi constant (bits of MAGICF)

typedef __attribute__((ext_vector_type(8))) short bf16x8;
typedef __attribute__((ext_vector_type(4))) float f32x4;

__device__ inline ushort f2b(float v) {
  union { float f; uint32_t u; } c; c.f = v;
  return (ushort)((c.u + 0x7FFF + ((c.u >> 16) & 1)) >> 16);  // RNE
}
__device__ inline float b2f(ushort h) {
  union { uint32_t u; float f; } c; c.u = ((uint32_t)h) << 16;
  return c.f;
}
__device__ inline uint32_t fxbits(float xf) {  // 0x4B400000 + round_ne(xf*2^19)
  union { float f; uint32_t u; } c;
  c.f = fmaf(xf, FPS, MAGICF);
  return c.u;
}

// ---- 1: merged prep: partition (blocks 0..EB-1) | W^T (8) | x->bf16 (rest) ----
__global__ __launch_bounds__(512) void k_prep(const float* __restrict__ x,
                                              const float* __restrict__ Wl,
                                              const float* __restrict__ Wr,
                                              const int* __restrict__ esrc,
                                              const int* __restrict__ edst,
                                              int* __restrict__ cursorB,
                                              int* __restrict__ degG,
                                              uint32_t* __restrict__ pairs,
                                              ushort* __restrict__ xb,
                                              ushort* __restrict__ WlT,
                                              ushort* __restrict__ WrT, int E,
                                              int EB, int xquads) {
  const int bid = blockIdx.x;
  const int t = threadIdx.x;

  if (bid >= EB) {
    if (bid < EB + 8) {  // W transpose: 8 blocks x 512 = 4096 elements
      const int idx = (bid - EB) * 512 + t;
      const int f = idx >> 6, k = idx & 63;
      WlT[f * 64 + k] = f2b(Wl[k * 64 + f]);
      WrT[f * 64 + k] = f2b(Wr[k * 64 + f]);
    } else {  // x -> bf16
      const int idx = (bid - EB - 8) * 512 + t;
      if (idx < xquads) {
        const float4 v = ((const float4*)x)[idx];
        ushort4 o;
        o.x = f2b(v.x); o.y = f2b(v.y); o.z = f2b(v.z); o.w = f2b(v.w);
        ((ushort4*)xb)[idx] = o;
      }
    }
    return;
  }

  // ---- partition: pure streaming, no LDS, no barriers ----
  const int base = bid * 4096;
  int s[8], d[8], sl[8];
#pragma unroll
  for (int i = 0; i < 8; ++i) {
    const int e = base + i * 512 + t;
    if (e < E) {
      s[i] = esrc[e];
      d[i] = edst[e];
    } else {
      d[i] = -1;
    }
  }
#pragma unroll
  for (int i = 0; i < 8; ++i)
    if (d[i] >= 0) sl[i] = atomicAdd(&cursorB[(d[i] >> 7) << 3], 1);
#pragma unroll
  for (int i = 0; i < 8; ++i)
    if (d[i] >= 0) {
      atomicAdd(&degG[d[i]], 1);
      pairs[(((uint32_t)d[i] >> 7) << CAPSH) + sl[i]] =
          (uint32_t)s[i] | ((uint32_t)(d[i] & (NPB - 1)) << 24);
    }
}

// ---- 2: fused streaming aggregation + MFMA GEMM (128 nodes / block) ----
// Gather: lanes c=t&15 (8B feature slice), slot=t>>4 (edge slot 0..31);
// 32 edges/pass x U=8 unroll. Per edge-lane: 2 paired ds_add_u64
// (magic-fma fixed-point, ~10 VALU). deg comes from degG (prep) -> no DS
// deg atomic, no c==0 divergence.
// MFMA: wave w = 16-node tile; loops 4 feature slices.
__global__ __launch_bounds__(512, 8) void k_fused(
    const ushort* __restrict__ xb, const int* __restrict__ cursorB,
    const int* __restrict__ degG, const uint32_t* __restrict__ pairs,
    const ushort* __restrict__ WlT, const ushort* __restrict__ WrT,
    float* __restrict__ out, int n_nodes) {
  __shared__ int accI[NPB][ACCW];
  const int b = blockIdx.x;
  const int t = threadIdx.x;
  const int wave = t >> 6;
  const int lane = t & 63;
  const int c = t & 15;
  const int slot = t >> 4;  // 0..31
  const int nodebase = b * NPB;

  {
    int* af = &accI[0][0];
    for (int i = t; i < NPB * ACCW; i += 512) af[i] = 0;
  }
  __syncthreads();

  const uint32_t rbase = (uint32_t)b << CAPSH;
  const int ecnt = cursorB[b << 3];

  for (int base0 = 0; base0 < ecnt; base0 += 256) {
    uint32_t p[8];
#pragma unroll
    for (int u = 0; u < 8; ++u) {
      const int e = base0 + u * 32 + slot;
      p[u] = (e < ecnt) ? pairs[rbase + e] : 0xFFFFFFFFu;
    }
    ushort4 h[8];
#pragma unroll
    for (int u = 0; u < 8; ++u)
      if (p[u] != 0xFFFFFFFFu)
        h[u] = *(const ushort4*)(xb + (size_t)(p[u] & 0xFFFFFFu) * FDIM +
                                 (c << 2));
#pragma unroll
    for (int u = 0; u < 8; ++u)
      if (p[u] != 0xFFFFFFFFu) {
        const int dl = p[u] >> 24;
        unsigned long long* a64 = (unsigned long long*)&accI[dl][c << 2];
        const uint32_t lo0 = fxbits(b2f(h[u].x)) & 0x007FFFFFu;
        const uint32_t hi0 = fxbits(b2f(h[u].y));
        const uint32_t lo1 = fxbits(b2f(h[u].z)) & 0x007FFFFFu;
        const uint32_t hi1 = fxbits(b2f(h[u].w));
        atomicAdd(a64, ((unsigned long long)hi0 << 32) | lo0);
        atomicAdd(a64 + 1, ((unsigned long long)hi1 << 32) | lo1);
      }
  }
  __syncthreads();

  // MFMA phase: 8 waves x 16-node tiles
  {
    const int m = lane & 15;
    const int quad = lane >> 4;
    const int lrow = wave * 16 + m;
    const int node = nodebase + lrow;
    const int dg = (node < n_nodes) ? degG[node] : 0;
    const uint32_t dbl = (uint32_t)dg * LOB;  // lo-half bias total
    const uint32_t dbh = (uint32_t)dg * HIB;  // hi-half const total (wraps ok)
    const float inv = FPINV / (float)max(dg, 1);
    bf16x8 am0, am1;
#pragma unroll
    for (int j = 0; j < 8; ++j) {
      const int k = quad * 8 + j;  // comp parity = j&1 (quad*8 even)
      const uint32_t db = (j & 1) ? dbh : dbl;
      const int s0 = (int)((uint32_t)accI[lrow][k] - db);
      const int s1 = (int)((uint32_t)accI[lrow][32 + k] - db);
      am0[j] = (short)f2b((float)s0 * inv);
      am1[j] = (short)f2b((float)s1 * inv);
    }
    const int arow = min(node, n_nodes - 1);
    bf16x8 ax0 = *(const bf16x8*)(xb + (size_t)arow * FDIM + quad * 8);
    bf16x8 ax1 = *(const bf16x8*)(xb + (size_t)arow * FDIM + 32 + quad * 8);
#pragma unroll
    for (int fs = 0; fs < 4; ++fs) {
      const int f = fs * 16 + m;
      bf16x8 bl0 = *(const bf16x8*)(WlT + (size_t)f * FDIM + quad * 8);
      bf16x8 bl1 = *(const bf16x8*)(WlT + (size_t)f * FDIM + 32 + quad * 8);
      bf16x8 br0 = *(const bf16x8*)(WrT + (size_t)f * FDIM + quad * 8);
      bf16x8 br1 = *(const bf16x8*)(WrT + (size_t)f * FDIM + 32 + quad * 8);
      f32x4 acc4 = {0.f, 0.f, 0.f, 0.f};
      acc4 = __builtin_amdgcn_mfma_f32_16x16x32_bf16(am0, bl0, acc4, 0, 0, 0);
      acc4 = __builtin_amdgcn_mfma_f32_16x16x32_bf16(am1, bl1, acc4, 0, 0, 0);
      acc4 = __builtin_amdgcn_mfma_f32_16x16x32_bf16(ax0, br0, acc4, 0, 0, 0);
      acc4 = __builtin_amdgcn_mfma_f32_16x16x32_bf16(ax1, br1, acc4, 0, 0, 0);
#pragma unroll
      for (int r = 0; r < 4; ++r) {
        const int onode = nodebase + wave * 16 + quad * 4 + r;
        if (onode < n_nodes) out[(size_t)onode * FDIM + fs * 16 + m] = acc4[r];
      }
    }
  }
}

extern "C" void kernel_launch(void* const* d_in, const int* in_sizes, int n_in,
                              void* d_out, int out_size, void* d_ws, size_t ws_size,
                              hipStream_t stream) {
  const float* x = (const float*)d_in[0];
  const int* edge_index = (const int*)d_in[1];
  const float* Wl = (const float*)d_in[2];
  const float* Wr = (const float*)d_in[3];
  float* out = (float*)d_out;

  const int n_nodes = in_sizes[0] / FDIM;  // 100000
  const int n_edges = in_sizes[1] / 2;     // 1200000
  const int* e_src = edge_index;
  const int* e_dst = edge_index + n_edges;

  const int NB2 = (n_nodes + NPB - 1) / NPB;  // 782

  // ws layout
  int* cursorB = (int*)d_ws;               // NBKTP*8 ints (32 KB)
  int* degG = cursorB + NBKTP * 8;         // N ints
  uint32_t* pairs = (uint32_t*)(degG + n_nodes);  // (NB2+1)*CAP u32
  ushort* xbuf = (ushort*)(((uintptr_t)(pairs + ((size_t)(NB2 + 1) << CAPSH)) +
                            15) & ~(uintptr_t)15);  // N*64 bf16
  ushort* WlT = xbuf + (size_t)n_nodes * FDIM;      // 4096
  ushort* WrT = WlT + FDIM * FDIM;                  // 4096

  const int xquads = n_nodes * (FDIM / 4);      // 1.6M float4 units
  const int XB2 = (xquads + 511) / 512;         // 3125
  const int EB = (n_edges + 4095) / 4096;       // 293

  hipMemsetAsync(cursorB, 0, (NBKTP * 8 + n_nodes) * sizeof(int), stream);
  k_prep<<<EB + 8 + XB2, 512, 0, stream>>>(x, Wl, Wr, e_src, e_dst, cursorB,
                                           degG, pairs, xbuf, WlT, WrT, n_edges,
                                           EB, xquads);
  k_fused<<<NB2, 512, 0, stream>>>(xbuf, cursorB, degG, pairs, WlT, WrT, out,
                                   n_nodes);
}

// Round 7
// 137.096 us; speedup vs baseline: 1.7142x; 1.7142x over previous
//
#include <hip/hip_runtime.h>
#include <stdint.h>

// SAGEConv (mean aggr, no bias): out = segment_mean(x[src], dst) @ W_l + x @ W_r
// Pipeline (memset + 2 kernels):
//   memset : cursorB[1024] = 0 (4 KB)
//   k_prep : block-role split:
//              [0,EB)    : partition edges into padded dst-buckets (dst>>7),
//                          LDS histogram + 2-counter shfl scan + LDS-staged
//                          coalesced scatter (round-4 proven path; global
//                          per-edge cursor atomics were a 121us disaster)
//              [EB,EB+8) : Wl/Wr transpose -> bf16
//              [EB+8,..) : x -> bf16 (overlaps partition)
//   k_fused: per bucket (128 nodes): stream packed edges, LDS fixed-point
//            accumulation via PAIRED ds_add_u64 (fp32 LDS atomicAdd is a
//            CAS-loop disaster on gfx950; u64 int add is native)
//            -> mean -> bf16 -> MFMA GEMM: out = mean@Wl + x@Wr
//
// Magic-number fixed-point (validated r5/r6): bits(fmaf(xf,2^19,1.5*2^23)) =
// 0x4B400000 + round_ne(xf*2^19). lo half of u64: masked 23 bits (per-addend
// bias 2^22); hi half keeps 0x4B400000, wraps mod 2^32 (removed as deg*const
// at epilogue). lo-half sum <= deg*2^23 < 2^32 for deg < 512 (max ~45 here).
// Quantization 2^-19 ~ 2e-6 << 0.03 tol; integer adds commute -> bit-stable.
//
// Geometry: NPB=128 -> accI[128][66] = 33.8 KB LDS; 512 thr (8 waves) ->
// 4 blocks/CU = 32 waves/CU. Pairs packed u32 = src | (dl<<24).

#define FDIM 64
#define NPB 128     // nodes per bucket (bucket = dst>>7)
#define ACCW 66     // padded int row stride (even: u64-aligned rows)
#define MAXBKT 1024 // bucket bound (782 used at N=100000)
#define PART_T 4096
#define CAP 2560    // per-bucket edge capacity (avg 1535, sd ~39 -> +26 sigma)
#define FPS 524288.0f        // 2^19
#define FPINV (1.0f / 524288.0f)
#define MAGICF 12582912.0f   // 1.5 * 2^23
#define LOB 0x00400000u      // per-addend lo bias 2^22
#define HIB 0x4B400000u      // per-addend hi constant (bits of MAGICF)

typedef __attribute__((ext_vector_type(8))) short bf16x8;
typedef __attribute__((ext_vector_type(4))) float f32x4;

__device__ inline ushort f2b(float v) {
  union { float f; uint32_t u; } c; c.f = v;
  return (ushort)((c.u + 0x7FFF + ((c.u >> 16) & 1)) >> 16);  // RNE
}
__device__ inline float b2f(ushort h) {
  union { uint32_t u; float f; } c; c.u = ((uint32_t)h) << 16;
  return c.f;
}
__device__ inline uint32_t fxbits(float xf) {  // 0x4B400000 + round_ne(xf*2^19)
  union { float f; uint32_t u; } c;
  c.f = fmaf(xf, FPS, MAGICF);
  return c.u;
}

// ---- 1: merged prep: partition (blocks 0..EB-1) | W^T (8) | x->bf16 (rest) ----
__global__ __launch_bounds__(512) void k_prep(const float* __restrict__ x,
                                              const float* __restrict__ Wl,
                                              const float* __restrict__ Wr,
                                              const int* __restrict__ esrc,
                                              const int* __restrict__ edst,
                                              int* __restrict__ cursorB,
                                              uint32_t* __restrict__ pairs,
                                              ushort* __restrict__ xb,
                                              ushort* __restrict__ WlT,
                                              ushort* __restrict__ WrT, int E,
                                              int EB, int xquads) {
  __shared__ int cnt[MAXBKT], excl0[MAXBKT], cursorL[MAXBKT], gbase[MAXBKT];
  __shared__ int wsum[8];
  __shared__ int2 buf[PART_T];
  const int bid = blockIdx.x;
  const int t = threadIdx.x;

  if (bid >= EB) {
    if (bid < EB + 8) {  // W transpose: 8 blocks x 512 = 4096 elements
      const int idx = (bid - EB) * 512 + t;
      const int f = idx >> 6, k = idx & 63;
      WlT[f * 64 + k] = f2b(Wl[k * 64 + f]);
      WrT[f * 64 + k] = f2b(Wr[k * 64 + f]);
    } else {  // x -> bf16
      const int idx = (bid - EB - 8) * 512 + t;
      if (idx < xquads) {
        const float4 v = ((const float4*)x)[idx];
        ushort4 o;
        o.x = f2b(v.x); o.y = f2b(v.y); o.z = f2b(v.z); o.w = f2b(v.w);
        ((ushort4*)xb)[idx] = o;
      }
    }
    return;
  }

  // ---- partition ----
  const int base = bid * PART_T;
  const int nvalid = min(E - base, PART_T);
  const int lane = t & 63;
  const int w = t >> 6;

  cnt[t] = 0;
  cnt[t + 512] = 0;
  __syncthreads();

  int s[8], d[8], bk[8];
#pragma unroll
  for (int i = 0; i < 8; ++i) {
    const int e = base + i * 512 + t;
    if (e < E) {
      s[i] = esrc[e];
      d[i] = edst[e];
      bk[i] = d[i] >> 7;
      atomicAdd(&cnt[bk[i]], 1);
    } else {
      bk[i] = -1;
    }
  }
  __syncthreads();

  // hierarchical scan of cnt[1024], 2 counters per thread
  const int c0 = cnt[2 * t], c1 = cnt[2 * t + 1];
  const int ts = c0 + c1;
  int v = ts;
#pragma unroll
  for (int off = 1; off < 64; off <<= 1) {
    int n = __shfl_up(v, off, 64);
    if (lane >= off) v += n;
  }
  if (lane == 63) wsum[w] = v;
  __syncthreads();
  if (t < 8) {
    int sv = wsum[t];
#pragma unroll
    for (int off = 1; off < 8; off <<= 1) {
      int n = __shfl_up(sv, off, 8);
      if (t >= off) sv += n;
    }
    wsum[t] = sv;
  }
  __syncthreads();
  const int ex = v - ts + (w > 0 ? wsum[w - 1] : 0);
  excl0[2 * t] = ex;
  cursorL[2 * t] = ex;
  excl0[2 * t + 1] = ex + c0;
  cursorL[2 * t + 1] = ex + c0;
  __syncthreads();

  // global base (atomic latency overlaps LDS scatter below)
  if (c0 > 0) gbase[2 * t] = 2 * t * CAP + atomicAdd(&cursorB[2 * t], c0);
  if (c1 > 0)
    gbase[2 * t + 1] = (2 * t + 1) * CAP + atomicAdd(&cursorB[2 * t + 1], c1);
#pragma unroll
  for (int i = 0; i < 8; ++i) {
    if (bk[i] >= 0) {
      int slot = atomicAdd(&cursorL[bk[i]], 1);
      buf[slot] = make_int2(s[i], d[i]);
    }
  }
  __syncthreads();

  for (int idx = t; idx < nvalid; idx += 512) {
    int2 p = buf[idx];
    int b = p.y >> 7;
    pairs[gbase[b] + (idx - excl0[b])] =
        (uint32_t)p.x | ((uint32_t)(p.y & (NPB - 1)) << 24);
  }
}

// ---- 2: fused streaming aggregation + MFMA GEMM (128 nodes / block) ----
// Gather: lanes c=t&15 (8B feature slice), slot=t>>4 (edge slot 0..31);
// 32 edges/pass x U=8 unroll. Per edge-lane: 2 paired ds_add_u64
// (magic-fma fixed-point, ~10 VALU). Main loop unpredicated (full 256-edge
// passes); single predicated tail pass.
// MFMA: wave w = 16-node tile; loops 4 feature slices.
__global__ __launch_bounds__(512, 8) void k_fused(
    const ushort* __restrict__ xb, const int* __restrict__ cursorB,
    const uint32_t* __restrict__ pairs, const ushort* __restrict__ WlT,
    const ushort* __restrict__ WrT, float* __restrict__ out, int n_nodes) {
  __shared__ int accI[NPB][ACCW];
  __shared__ int deg[NPB];
  const int b = blockIdx.x;
  const int t = threadIdx.x;
  const int wave = t >> 6;
  const int lane = t & 63;
  const int c = t & 15;
  const int slot = t >> 4;  // 0..31
  const int nodebase = b * NPB;

  {
    int2* af = (int2*)&accI[0][0];
    for (int i = t; i < NPB * ACCW / 2; i += 512) af[i] = make_int2(0, 0);
    if (t < NPB) deg[t] = 0;
  }
  __syncthreads();

  const int rbase = b * CAP;
  const int ecnt = cursorB[b];
  const int full = ecnt & ~255;  // steady-state passes: all 256 edges valid

  for (int base0 = 0; base0 < full; base0 += 256) {
    uint32_t p[8];
#pragma unroll
    for (int u = 0; u < 8; ++u) p[u] = pairs[rbase + base0 + u * 32 + slot];
    ushort4 h[8];
#pragma unroll
    for (int u = 0; u < 8; ++u)
      h[u] = *(const ushort4*)(xb + (size_t)(p[u] & 0xFFFFFFu) * FDIM +
                               (c << 2));
#pragma unroll
    for (int u = 0; u < 8; ++u) {
      const int dl = p[u] >> 24;
      unsigned long long* a64 = (unsigned long long*)&accI[dl][c << 2];
      const uint32_t lo0 = fxbits(b2f(h[u].x)) & 0x007FFFFFu;
      const uint32_t hi0 = fxbits(b2f(h[u].y));
      const uint32_t lo1 = fxbits(b2f(h[u].z)) & 0x007FFFFFu;
      const uint32_t hi1 = fxbits(b2f(h[u].w));
      atomicAdd(a64, ((unsigned long long)hi0 << 32) | lo0);
      atomicAdd(a64 + 1, ((unsigned long long)hi1 << 32) | lo1);
      if (c == 0) atomicAdd(&deg[dl], 1);
    }
  }
  // tail pass (< 256 edges), predicated
  if (full < ecnt) {
    uint32_t p[8];
#pragma unroll
    for (int u = 0; u < 8; ++u) {
      const int e = full + u * 32 + slot;
      p[u] = (e < ecnt) ? pairs[rbase + e] : 0xFFFFFFFFu;
    }
    ushort4 h[8];
#pragma unroll
    for (int u = 0; u < 8; ++u)
      if (p[u] != 0xFFFFFFFFu)
        h[u] = *(const ushort4*)(xb + (size_t)(p[u] & 0xFFFFFFu) * FDIM +
                                 (c << 2));
#pragma unroll
    for (int u = 0; u < 8; ++u)
      if (p[u] != 0xFFFFFFFFu) {
        const int dl = p[u] >> 24;
        unsigned long long* a64 = (unsigned long long*)&accI[dl][c << 2];
        const uint32_t lo0 = fxbits(b2f(h[u].x)) & 0x007FFFFFu;
        const uint32_t hi0 = fxbits(b2f(h[u].y));
        const uint32_t lo1 = fxbits(b2f(h[u].z)) & 0x007FFFFFu;
        const uint32_t hi1 = fxbits(b2f(h[u].w));
        atomicAdd(a64, ((unsigned long long)hi0 << 32) | lo0);
        atomicAdd(a64 + 1, ((unsigned long long)hi1 << 32) | lo1);
        if (c == 0) atomicAdd(&deg[dl], 1);
      }
  }
  __syncthreads();

  // MFMA phase: 8 waves x 16-node tiles
  {
    const int m = lane & 15;
    const int quad = lane >> 4;
    const int lrow = wave * 16 + m;
    const int node = nodebase + lrow;
    const int dg = deg[lrow];
    const uint32_t dbl = (uint32_t)dg * LOB;  // lo-half bias total
    const uint32_t dbh = (uint32_t)dg * HIB;  // hi-half const total (wraps ok)
    const float inv = FPINV / (float)max(dg, 1);
    bf16x8 am0, am1;
#pragma unroll
    for (int j = 0; j < 8; ++j) {
      const int k = quad * 8 + j;  // comp parity = j&1 (quad*8 even)
      const uint32_t db = (j & 1) ? dbh : dbl;
      const int s0 = (int)((uint32_t)accI[lrow][k] - db);
      const int s1 = (int)((uint32_t)accI[lrow][32 + k] - db);
      am0[j] = (short)f2b((float)s0 * inv);
      am1[j] = (short)f2b((float)s1 * inv);
    }
    const int arow = min(node, n_nodes - 1);
    bf16x8 ax0 = *(const bf16x8*)(xb + (size_t)arow * FDIM + quad * 8);
    bf16x8 ax1 = *(const bf16x8*)(xb + (size_t)arow * FDIM + 32 + quad * 8);
#pragma unroll
    for (int fs = 0; fs < 4; ++fs) {
      const int f = fs * 16 + m;
      bf16x8 bl0 = *(const bf16x8*)(WlT + (size_t)f * FDIM + quad * 8);
      bf16x8 bl1 = *(const bf16x8*)(WlT + (size_t)f * FDIM + 32 + quad * 8);
      bf16x8 br0 = *(const bf16x8*)(WrT + (size_t)f * FDIM + quad * 8);
      bf16x8 br1 = *(const bf16x8*)(WrT + (size_t)f * FDIM + 32 + quad * 8);
      f32x4 acc4 = {0.f, 0.f, 0.f, 0.f};
      acc4 = __builtin_amdgcn_mfma_f32_16x16x32_bf16(am0, bl0, acc4, 0, 0, 0);
      acc4 = __builtin_amdgcn_mfma_f32_16x16x32_bf16(am1, bl1, acc4, 0, 0, 0);
      acc4 = __builtin_amdgcn_mfma_f32_16x16x32_bf16(ax0, br0, acc4, 0, 0, 0);
      acc4 = __builtin_amdgcn_mfma_f32_16x16x32_bf16(ax1, br1, acc4, 0, 0, 0);
#pragma unroll
      for (int r = 0; r < 4; ++r) {
        const int onode = nodebase + wave * 16 + quad * 4 + r;
        if (onode < n_nodes) out[(size_t)onode * FDIM + fs * 16 + m] = acc4[r];
      }
    }
  }
}

extern "C" void kernel_launch(void* const* d_in, const int* in_sizes, int n_in,
                              void* d_out, int out_size, void* d_ws, size_t ws_size,
                              hipStream_t stream) {
  const float* x = (const float*)d_in[0];
  const int* edge_index = (const int*)d_in[1];
  const float* Wl = (const float*)d_in[2];
  const float* Wr = (const float*)d_in[3];
  float* out = (float*)d_out;

  const int n_nodes = in_sizes[0] / FDIM;  // 100000
  const int n_edges = in_sizes[1] / 2;     // 1200000
  const int* e_src = edge_index;
  const int* e_dst = edge_index + n_edges;

  const int NB2 = (n_nodes + NPB - 1) / NPB;  // 782

  // ws layout
  int* cursorB = (int*)d_ws;  // MAXBKT
  uint32_t* pairs = (uint32_t*)(cursorB + MAXBKT);  // (NB2+1)*CAP u32
  ushort* xbuf = (ushort*)(((uintptr_t)(pairs + (size_t)(NB2 + 1) * CAP) + 15) &
                           ~(uintptr_t)15);     // N*64 bf16
  ushort* WlT = xbuf + (size_t)n_nodes * FDIM;  // 4096
  ushort* WrT = WlT + FDIM * FDIM;              // 4096

  const int xquads = n_nodes * (FDIM / 4);         // 1.6M float4 units
  const int XB2 = (xquads + 511) / 512;            // 3125
  const int EB = (n_edges + PART_T - 1) / PART_T;  // 293

  hipMemsetAsync(cursorB, 0, MAXBKT * sizeof(int), stream);
  k_prep<<<EB + 8 + XB2, 512, 0, stream>>>(x, Wl, Wr, e_src, e_dst, cursorB,
                                           pairs, xbuf, WlT, WrT, n_edges, EB,
                                           xquads);
  k_fused<<<NB2, 512, 0, stream>>>(xbuf, cursorB, pairs, WlT, WrT, out, n_nodes);
}

// Round 8
// 134.268 us; speedup vs baseline: 1.7503x; 1.0211x over previous
//
#include <hip/hip_runtime.h>
#include <stdint.h>

// SAGEConv (mean aggr, no bias): out = segment_mean(x[src], dst) @ W_l + x @ W_r
// Pipeline (memset + 2 kernels):
//   memset : cursorB[2048] = 0 (8 KB)
//   k_prep : block-role split:
//              [0,EB)    : partition edges into padded dst-buckets (dst>>6):
//                          LDS histogram -> ONE global atomicAdd per
//                          (block,bucket) range-reserve -> direct scatter via
//                          LDS cursors. No scan, no staging buf, 8 KB LDS.
//                          (r6 showed per-EDGE global cursors are a disaster;
//                           r4/r7 staging+scan is dead weight: pairs writes
//                           are L2-absorbed regardless of order.)
//              [EB,EB+8) : Wl/Wr transpose -> bf16
//              [EB+8,..) : x -> bf16 (overlaps partition)
//   k_fused: per bucket (64 nodes): stream packed edges, LDS fixed-point
//            accumulation via PAIRED ds_add_u64 (fp32 LDS atomicAdd is a
//            CAS-loop disaster on gfx950; u64 int add is native)
//            -> mean -> bf16 -> MFMA GEMM: out = mean@Wl + x@Wr
//
// Magic-number fixed-point (validated r5-r7): bits(fmaf(xf,2^19,1.5*2^23)) =
// 0x4B400000 + round_ne(xf*2^19). lo half of u64: masked 23 bits (per-addend
// bias 2^22); hi half keeps 0x4B400000, wraps mod 2^32 (removed as deg*const
// at epilogue). lo-half sum <= deg*2^23 < 2^32 for deg < 512 (max ~45 here).
// Quantization 2^-19 ~ 2e-6 << 0.03 tol; integer adds commute -> bit-stable.
//
// Geometry: NPB=64 -> accI[64][66] = 16.9 KB LDS; 256 thr (4 waves) ->
// 8 blocks/CU = 32 waves/CU; 1563 blocks = 6.1/CU (CU imbalance ~15% vs 31%
// at NPB=128/3.05 per CU). Pairs packed u32 = src | (dl<<24).

#define FDIM 64
#define NPB 64      // nodes per bucket (bucket = dst>>6)
#define ACCW 66     // padded int row stride (even: u64-aligned rows)
#define MAXBKT 2048 // bucket bound (1563 used at N=100000)
#define PART_T 4096
#define CAP 1024    // per-bucket capacity (avg 768, sd 27.7 -> +9.2 sigma;
                    // expected max over 1563 buckets ~857)
#define CAPSH 10
#define FPS 524288.0f        // 2^19
#define FPINV (1.0f / 524288.0f)
#define MAGICF 12582912.0f   // 1.5 * 2^23
#define LOB 0x00400000u      // per-addend lo bias 2^22
#define HIB 0x4B400000u      // per-addend hi constant (bits of MAGICF)

typedef __attribute__((ext_vector_type(8))) short bf16x8;
typedef __attribute__((ext_vector_type(4))) float f32x4;

__device__ inline ushort f2b(float v) {
  union { float f; uint32_t u; } c; c.f = v;
  return (ushort)((c.u + 0x7FFF + ((c.u >> 16) & 1)) >> 16);  // RNE
}
__device__ inline float b2f(ushort h) {
  union { uint32_t u; float f; } c; c.u = ((uint32_t)h) << 16;
  return c.f;
}
__device__ inline uint32_t fxbits(float xf) {  // 0x4B400000 + round_ne(xf*2^19)
  union { float f; uint32_t u; } c;
  c.f = fmaf(xf, FPS, MAGICF);
  return c.u;
}

// ---- 1: merged prep: partition (blocks 0..EB-1) | W^T (8) | x->bf16 (rest) ----
__global__ __launch_bounds__(512) void k_prep(const float* __restrict__ x,
                                              const float* __restrict__ Wl,
                                              const float* __restrict__ Wr,
                                              const int* __restrict__ esrc,
                                              const int* __restrict__ edst,
                                              int* __restrict__ cursorB,
                                              uint32_t* __restrict__ pairs,
                                              ushort* __restrict__ xb,
                                              ushort* __restrict__ WlT,
                                              ushort* __restrict__ WrT, int E,
                                              int EB, int xquads) {
  __shared__ int cnt[MAXBKT];  // histogram -> (reused) global write cursor
  const int bid = blockIdx.x;
  const int t = threadIdx.x;

  if (bid >= EB) {
    if (bid < EB + 8) {  // W transpose: 8 blocks x 512 = 4096 elements
      const int idx = (bid - EB) * 512 + t;
      const int f = idx >> 6, k = idx & 63;
      WlT[f * 64 + k] = f2b(Wl[k * 64 + f]);
      WrT[f * 64 + k] = f2b(Wr[k * 64 + f]);
    } else {  // x -> bf16
      const int idx = (bid - EB - 8) * 512 + t;
      if (idx < xquads) {
        const float4 v = ((const float4*)x)[idx];
        ushort4 o;
        o.x = f2b(v.x); o.y = f2b(v.y); o.z = f2b(v.z); o.w = f2b(v.w);
        ((ushort4*)xb)[idx] = o;
      }
    }
    return;
  }

  // ---- partition: histogram -> range-reserve -> direct scatter ----
  const int base = bid * PART_T;
  cnt[t] = 0;
  cnt[t + 512] = 0;
  cnt[t + 1024] = 0;
  cnt[t + 1536] = 0;
  __syncthreads();

  int s[8], d[8];
#pragma unroll
  for (int i = 0; i < 8; ++i) {
    const int e = base + i * 512 + t;
    if (e < E) {
      s[i] = esrc[e];
      d[i] = edst[e];
      atomicAdd(&cnt[d[i] >> 6], 1);
    } else {
      d[i] = -1;
    }
  }
  __syncthreads();

  // reserve global ranges: one global atomic per (block, nonzero bucket);
  // cnt[b] becomes the absolute write cursor for this block's share.
#pragma unroll
  for (int i = 0; i < 4; ++i) {
    const int b = t + i * 512;
    const int cb = cnt[b];
    if (cb > 0) cnt[b] = (b << CAPSH) + atomicAdd(&cursorB[b], cb);
  }
  __syncthreads();  // compiler emits vmcnt(0) before s_barrier -> bases valid

#pragma unroll
  for (int i = 0; i < 8; ++i) {
    if (d[i] >= 0) {
      const int slot = atomicAdd(&cnt[d[i] >> 6], 1);
      pairs[slot] = (uint32_t)s[i] | ((uint32_t)(d[i] & (NPB - 1)) << 24);
    }
  }
}

// ---- 2: fused streaming aggregation + MFMA GEMM (64 nodes / block) ----
// Gather: lanes c=t&15 (8B feature slice), slot=t>>4 (edge slot 0..15);
// 16 edges/pass x U=8 unroll. Per edge-lane: 2 paired ds_add_u64
// (magic-fma fixed-point). Main loop unpredicated (full 128-edge passes);
// single predicated tail pass. MFMA: wave w = 16-node tile; 4 f-slices.
__global__ __launch_bounds__(256, 8) void k_fused(
    const ushort* __restrict__ xb, const int* __restrict__ cursorB,
    const uint32_t* __restrict__ pairs, const ushort* __restrict__ WlT,
    const ushort* __restrict__ WrT, float* __restrict__ out, int n_nodes) {
  __shared__ int accI[NPB][ACCW];
  __shared__ int deg[NPB];
  const int b = blockIdx.x;
  const int t = threadIdx.x;
  const int wave = t >> 6;
  const int lane = t & 63;
  const int c = t & 15;
  const int slot = t >> 4;  // 0..15
  const int nodebase = b * NPB;

  {
    int2* af = (int2*)&accI[0][0];
    for (int i = t; i < NPB * ACCW / 2; i += 256) af[i] = make_int2(0, 0);
    if (t < NPB) deg[t] = 0;
  }
  __syncthreads();

  const int rbase = b << CAPSH;
  const int ecnt = cursorB[b];
  const int full = ecnt & ~127;  // steady-state passes: all 128 edges valid

  for (int base0 = 0; base0 < full; base0 += 128) {
    uint32_t p[8];
#pragma unroll
    for (int u = 0; u < 8; ++u) p[u] = pairs[rbase + base0 + u * 16 + slot];
    ushort4 h[8];
#pragma unroll
    for (int u = 0; u < 8; ++u)
      h[u] = *(const ushort4*)(xb + (size_t)(p[u] & 0xFFFFFFu) * FDIM +
                               (c << 2));
#pragma unroll
    for (int u = 0; u < 8; ++u) {
      const int dl = p[u] >> 24;
      unsigned long long* a64 = (unsigned long long*)&accI[dl][c << 2];
      const uint32_t lo0 = fxbits(b2f(h[u].x)) & 0x007FFFFFu;
      const uint32_t hi0 = fxbits(b2f(h[u].y));
      const uint32_t lo1 = fxbits(b2f(h[u].z)) & 0x007FFFFFu;
      const uint32_t hi1 = fxbits(b2f(h[u].w));
      atomicAdd(a64, ((unsigned long long)hi0 << 32) | lo0);
      atomicAdd(a64 + 1, ((unsigned long long)hi1 << 32) | lo1);
      if (c == 0) atomicAdd(&deg[dl], 1);
    }
  }
  // tail pass (< 128 edges), predicated
  if (full < ecnt) {
    uint32_t p[8];
#pragma unroll
    for (int u = 0; u < 8; ++u) {
      const int e = full + u * 16 + slot;
      p[u] = (e < ecnt) ? pairs[rbase + e] : 0xFFFFFFFFu;
    }
    ushort4 h[8];
#pragma unroll
    for (int u = 0; u < 8; ++u)
      if (p[u] != 0xFFFFFFFFu)
        h[u] = *(const ushort4*)(xb + (size_t)(p[u] & 0xFFFFFFu) * FDIM +
                                 (c << 2));
#pragma unroll
    for (int u = 0; u < 8; ++u)
      if (p[u] != 0xFFFFFFFFu) {
        const int dl = p[u] >> 24;
        unsigned long long* a64 = (unsigned long long*)&accI[dl][c << 2];
        const uint32_t lo0 = fxbits(b2f(h[u].x)) & 0x007FFFFFu;
        const uint32_t hi0 = fxbits(b2f(h[u].y));
        const uint32_t lo1 = fxbits(b2f(h[u].z)) & 0x007FFFFFu;
        const uint32_t hi1 = fxbits(b2f(h[u].w));
        atomicAdd(a64, ((unsigned long long)hi0 << 32) | lo0);
        atomicAdd(a64 + 1, ((unsigned long long)hi1 << 32) | lo1);
        if (c == 0) atomicAdd(&deg[dl], 1);
      }
  }
  __syncthreads();

  // MFMA phase: 4 waves x 16-node tiles
  {
    const int m = lane & 15;
    const int quad = lane >> 4;
    const int lrow = wave * 16 + m;
    const int node = nodebase + lrow;
    const int dg = deg[lrow];
    const uint32_t dbl = (uint32_t)dg * LOB;  // lo-half bias total
    const uint32_t dbh = (uint32_t)dg * HIB;  // hi-half const total (wraps ok)
    const float inv = FPINV / (float)max(dg, 1);
    bf16x8 am0, am1;
#pragma unroll
    for (int j = 0; j < 8; ++j) {
      const int k = quad * 8 + j;  // comp parity = j&1 (quad*8 even)
      const uint32_t db = (j & 1) ? dbh : dbl;
      const int s0 = (int)((uint32_t)accI[lrow][k] - db);
      const int s1 = (int)((uint32_t)accI[lrow][32 + k] - db);
      am0[j] = (short)f2b((float)s0 * inv);
      am1[j] = (short)f2b((float)s1 * inv);
    }
    const int arow = min(node, n_nodes - 1);
    bf16x8 ax0 = *(const bf16x8*)(xb + (size_t)arow * FDIM + quad * 8);
    bf16x8 ax1 = *(const bf16x8*)(xb + (size_t)arow * FDIM + 32 + quad * 8);
#pragma unroll
    for (int fs = 0; fs < 4; ++fs) {
      const int f = fs * 16 + m;
      bf16x8 bl0 = *(const bf16x8*)(WlT + (size_t)f * FDIM + quad * 8);
      bf16x8 bl1 = *(const bf16x8*)(WlT + (size_t)f * FDIM + 32 + quad * 8);
      bf16x8 br0 = *(const bf16x8*)(WrT + (size_t)f * FDIM + quad * 8);
      bf16x8 br1 = *(const bf16x8*)(WrT + (size_t)f * FDIM + 32 + quad * 8);
      f32x4 acc4 = {0.f, 0.f, 0.f, 0.f};
      acc4 = __builtin_amdgcn_mfma_f32_16x16x32_bf16(am0, bl0, acc4, 0, 0, 0);
      acc4 = __builtin_amdgcn_mfma_f32_16x16x32_bf16(am1, bl1, acc4, 0, 0, 0);
      acc4 = __builtin_amdgcn_mfma_f32_16x16x32_bf16(ax0, br0, acc4, 0, 0, 0);
      acc4 = __builtin_amdgcn_mfma_f32_16x16x32_bf16(ax1, br1, acc4, 0, 0, 0);
#pragma unroll
      for (int r = 0; r < 4; ++r) {
        const int onode = nodebase + wave * 16 + quad * 4 + r;
        if (onode < n_nodes) out[(size_t)onode * FDIM + fs * 16 + m] = acc4[r];
      }
    }
  }
}

extern "C" void kernel_launch(void* const* d_in, const int* in_sizes, int n_in,
                              void* d_out, int out_size, void* d_ws, size_t ws_size,
                              hipStream_t stream) {
  const float* x = (const float*)d_in[0];
  const int* edge_index = (const int*)d_in[1];
  const float* Wl = (const float*)d_in[2];
  const float* Wr = (const float*)d_in[3];
  float* out = (float*)d_out;

  const int n_nodes = in_sizes[0] / FDIM;  // 100000
  const int n_edges = in_sizes[1] / 2;     // 1200000
  const int* e_src = edge_index;
  const int* e_dst = edge_index + n_edges;

  const int NB2 = (n_nodes + NPB - 1) / NPB;  // 1563

  // ws layout
  int* cursorB = (int*)d_ws;  // MAXBKT
  uint32_t* pairs = (uint32_t*)(cursorB + MAXBKT);  // (NB2+1)*CAP u32
  ushort* xbuf = (ushort*)(((uintptr_t)(pairs + ((size_t)(NB2 + 1) << CAPSH)) +
                            15) & ~(uintptr_t)15);  // N*64 bf16
  ushort* WlT = xbuf + (size_t)n_nodes * FDIM;      // 4096
  ushort* WrT = WlT + FDIM * FDIM;                  // 4096

  const int xquads = n_nodes * (FDIM / 4);         // 1.6M float4 units
  const int XB2 = (xquads + 511) / 512;            // 3125
  const int EB = (n_edges + PART_T - 1) / PART_T;  // 293

  hipMemsetAsync(cursorB, 0, MAXBKT * sizeof(int), stream);
  k_prep<<<EB + 8 + XB2, 512, 0, stream>>>(x, Wl, Wr, e_src, e_dst, cursorB,
                                           pairs, xbuf, WlT, WrT, n_edges, EB,
                                           xquads);
  k_fused<<<NB2, 256, 0, stream>>>(xbuf, cursorB, pairs, WlT, WrT, out, n_nodes);
}